// Round 9
// baseline (131.290 us; speedup 1.0000x reference)
//
#include <hip/hip_runtime.h>
#include <hip/hip_bf16.h>

// KAN linear == GEMM M=8192, N=512, K=4096 (8 Chebyshev/silu feats per input,
// basis_0 folded into bias). Round 18: R17 proved fetch-volume is not the
// limiter (FETCH 67.6->24.7 MB, wall -4us). We sit at the 2-phase-structure
// ceiling (~576 TF-equiv; m233/m248) and EVERY schedule experiment was null
// because 256-thread blocks = 1 wave/SIMD per barrier domain -> no role-split
// for T3/T4/T5 to exploit (m190 lockstep-null). R18: 512-thread blocks
// (8 waves = 2wm x 4kk, 4 waves/SIMD in ONE barrier domain), m201-style
// phased schedule: per K-tile (128 elems, 32 tiles) two phases of
// {ds_read ||stage-issue || gen -> barrier -> setprio 4xMFMA -> barrier},
// counted vmcnt(2) at tile boundary only (W issued ph0, x ph1 -> x rides
// the barrier). Math verbatim R13/R17: B mod-16 XOR swizzle, frag offsets,
// register-x GENSEL, XCD x-locality map. LDS 32 KB (2 blk/CU = 16 w/CU).
// Epilogue: 4-way split-K reduce via [v][lane] slabs (conflict-free, 32 KB).
#define IN_FEAT 512
#define OUT_FEAT 512
#define NTOK 8192
#define KDIM 4096

typedef short bf16x8 __attribute__((ext_vector_type(8)));
typedef float f32x16 __attribute__((ext_vector_type(16)));

static __device__ inline short f2bf(float f) {
    union { float f; unsigned u; } v; v.f = f;
    unsigned u = v.u;
    u += 0x7fffu + ((u >> 16) & 1u);   // RNE
    return (short)(u >> 16);
}

static __device__ inline unsigned cvtpk(float lo, float hi) {
    unsigned r;
    asm("v_cvt_pk_bf16_f32 %0, %1, %2" : "=v"(r) : "v"(lo), "v"(hi));
    return r;
}

// 8 basis features of one (token,input): [silu(xc), xc, T2..T7]
static __device__ inline bf16x8 gen_chunk(float xv) {
    float xc = fminf(fmaxf(xv, -1.f), 1.f);
    float e  = __expf(-xc);
    float bse = xc * __builtin_amdgcn_rcpf(1.f + e);
    float b2 = 2.f * xc * xc - 1.f;
    float b3 = 2.f * xc * b2 - 1.f;
    float b4 = 2.f * xc * b3 - 1.f;
    float b5 = 2.f * xc * b4 - 1.f;
    float b6 = 2.f * xc * b5 - 1.f;
    float b7 = 2.f * xc * b6 - 1.f;
    union { uint4 u; bf16x8 v; } r;
    r.u.x = cvtpk(bse, xc);
    r.u.y = cvtpk(b2, b3);
    r.u.z = cvtpk(b4, b5);
    r.u.w = cvtpk(b6, b7);
    return r.v;
}

static __device__ inline void gload_lds16(const short* g, short* l) {
    __builtin_amdgcn_global_load_lds(
        (const __attribute__((address_space(1))) unsigned int*)g,
        (__attribute__((address_space(3))) unsigned int*)l,
        16, 0, 0);
}

// ---------------- prep: W bf16 [512 x 4096] + folded bias ----------------
__global__ __launch_bounds__(256) void kan_prep(
    const float* __restrict__ coeff, const float* __restrict__ scale_base,
    const float* __restrict__ scale_spline, const float* __restrict__ base_bias,
    short* __restrict__ Wb, float* __restrict__ bias)
{
    int o = blockIdx.x;
    int tid = threadIdx.x;
    float local = 0.f;
#pragma unroll
    for (int rep = 0; rep < 2; ++rep) {
        int i = tid + rep * 256;
        size_t oi = (size_t)o * IN_FEAT + i;
        const float4* c4 = (const float4*)(coeff + oi * 8);
        float4 ca = c4[0], cb = c4[1];
        float ss = scale_spline[oi];
        float sb = scale_base[oi];
        local += base_bias[oi] + ss * ca.x;
        bf16x8 w;
        w[0] = f2bf(sb);
        w[1] = f2bf(ss * ca.y); w[2] = f2bf(ss * ca.z); w[3] = f2bf(ss * ca.w);
        w[4] = f2bf(ss * cb.x); w[5] = f2bf(ss * cb.y); w[6] = f2bf(ss * cb.z);
        w[7] = f2bf(ss * cb.w);
        *(bf16x8*)(Wb + (size_t)o * KDIM + (size_t)i * 8) = w;
    }
    __shared__ float red[4];
    for (int off = 32; off > 0; off >>= 1) local += __shfl_down(local, off, 64);
    int lane = tid & 63, wv = tid >> 6;
    if (lane == 0) red[wv] = local;
    __syncthreads();
    if (tid == 0) bias[o] = red[0] + red[1] + red[2] + red[3];
}

// -- 32x32x16 fused GEMM, 128m x 64n, 8 waves (2wm x 4kk), phased schedule --
__global__ __launch_bounds__(512, 4) void kan_gemm18(
    const float* __restrict__ x, const short* __restrict__ Wb,
    const float* __restrict__ bias, float* __restrict__ out)
{
    // LDS 32768 B: Bs dbuf [2][64 rows][16 slots][8 shorts]
    // (phys slot = g ^ (row&15), verbatim R13). Epilogue rbuf overlays.
    __shared__ __align__(16) short POOL[16384];
    short* Bs = POOL;                     // [2][8192]

    int tid = threadIdx.x;
    int bid = blockIdx.x;
    int j8 = bid & 7, t5 = bid >> 3;      // XCD x-locality map (verbatim R17)
    int mb = j8 * 8 + (t5 & 7);           // 64 m-tiles of 128 tokens
    int nb = t5 >> 3;                     // 8 n-tiles of 64 outs
    int m0 = mb * 128, o0 = nb * 64;

    int lane = tid & 63, wv = tid >> 6;   // 8 waves
    int wm = wv & 1, kk = wv >> 1;        // wave = 64m x 64n on K-quarter kk
    int l31 = lane & 31, half = lane >> 5;
    int rm  = l31 & 15;

    f32x16 acc[2][2];                     // [fm][fn], 32x32 each
#pragma unroll
    for (int a = 0; a < 2; ++a)
#pragma unroll
        for (int b = 0; b < 2; ++b) acc[a][b] = (f32x16)0.f;

    // B DMA (R13 swizzle, re-divided over 8 waves): wave stages rows
    // [wv*8,+8), 2 calls of 4 rows x 16 slots. call c, lane i:
    // row = wv*8 + c*4 + (i>>4), phys slot i&15 holds g = (i&15)^(row&15).
    int rl = lane >> 4, q = lane & 15;
    int ra = wv * 8 + rl, rb = ra + 4;
    const short* pBa = Wb + (size_t)(o0 + ra) * KDIM + (size_t)(q ^ (ra & 15)) * 8;
    const short* pBb = Wb + (size_t)(o0 + rb) * KDIM + (size_t)(q ^ (rb & 15)) * 8;
    int bda = (wv * 8) * 128;             // short offsets within a buffer
    int bdb = bda + 512;

    // x: wave (wm,kk) needs cols [kk*4,+4) of tokens m0+wm*64+{0,32}+l31
    // -> 2 aligned float4 per tile, register ring (R14-verified GENSEL).
    const float* xp0 = x + (size_t)(m0 + wm * 64 + l31) * IN_FEAT + kk * 4;

    // Frag-read offsets (verbatim R13): phase p col s = kk*4 + p*2 + half.
    int of0 = l31 * 128 + (((kk * 4 + 0 + half) ^ rm) * 8);
    int of1 = l31 * 128 + (((kk * 4 + 2 + half) ^ rm) * 8);

#define MFMA_(A, B, C) __builtin_amdgcn_mfma_f32_32x32x16_bf16(A, B, C, 0, 0, 0)

// PHASE0(t): ds_read of0 pair from buf CUR; issue W(t+1) (both calls) into
// buf CUR^1; gen x(t).xy; barrier; 4 MFMA; barrier.
#define PHASE0(CUR, IT1, PC0, PC1)                                            \
    {                                                                         \
        const short* Bc_ = Bs + (CUR) * 8192;                                 \
        bf16x8 b0_ = *(const bf16x8*)(Bc_ + of0);                             \
        bf16x8 b1_ = *(const bf16x8*)(Bc_ + of0 + 4096);                      \
        short* bd_ = Bs + ((CUR) ^ 1) * 8192;                                 \
        gload_lds16(pBa + (size_t)(IT1) * 128, bd_ + bda);                    \
        gload_lds16(pBb + (size_t)(IT1) * 128, bd_ + bdb);                    \
        bf16x8 a0_ = gen_chunk(half ? (PC0).y : (PC0).x);                     \
        bf16x8 a1_ = gen_chunk(half ? (PC1).y : (PC1).x);                     \
        __builtin_amdgcn_s_barrier();                                         \
        __builtin_amdgcn_s_setprio(1);                                        \
        acc[0][0] = MFMA_(a0_, b0_, acc[0][0]);                               \
        acc[0][1] = MFMA_(a0_, b1_, acc[0][1]);                               \
        acc[1][0] = MFMA_(a1_, b0_, acc[1][0]);                               \
        acc[1][1] = MFMA_(a1_, b1_, acc[1][1]);                               \
        __builtin_amdgcn_s_setprio(0);                                        \
        __builtin_amdgcn_s_barrier();                                         \
    }

// PHASE1(t): ds_read of1 pair; load x(t+1) regs; gen x(t).zw; barrier;
// 4 MFMA; vmcnt(2) drains W(t+1) (x(t+1) rides the barrier); barrier.
#define PHASE1(CUR, IT1, PC0, PC1, PN0, PN1)                                  \
    {                                                                         \
        const short* Bc_ = Bs + (CUR) * 8192;                                 \
        bf16x8 b0_ = *(const bf16x8*)(Bc_ + of1);                             \
        bf16x8 b1_ = *(const bf16x8*)(Bc_ + of1 + 4096);                      \
        const float* xq_ = xp0 + (size_t)(IT1) * 16;                          \
        PN0 = *(const float4*)(xq_);                                          \
        PN1 = *(const float4*)(xq_ + 16384);                                  \
        bf16x8 a0_ = gen_chunk(half ? (PC0).w : (PC0).z);                     \
        bf16x8 a1_ = gen_chunk(half ? (PC1).w : (PC1).z);                     \
        __builtin_amdgcn_s_barrier();                                         \
        __builtin_amdgcn_s_setprio(1);                                        \
        acc[0][0] = MFMA_(a0_, b0_, acc[0][0]);                               \
        acc[0][1] = MFMA_(a0_, b1_, acc[0][1]);                               \
        acc[1][0] = MFMA_(a1_, b0_, acc[1][0]);                               \
        acc[1][1] = MFMA_(a1_, b1_, acc[1][1]);                               \
        __builtin_amdgcn_s_setprio(0);                                        \
        asm volatile("s_waitcnt vmcnt(2)" ::: "memory");                      \
        __builtin_amdgcn_s_barrier();                                         \
    }

// Tail phases for tile 31 (no staging; x auto-waited by register dep).
#define PHASE0T(CUR, PC0, PC1)                                                \
    {                                                                         \
        const short* Bc_ = Bs + (CUR) * 8192;                                 \
        bf16x8 b0_ = *(const bf16x8*)(Bc_ + of0);                             \
        bf16x8 b1_ = *(const bf16x8*)(Bc_ + of0 + 4096);                      \
        bf16x8 a0_ = gen_chunk(half ? (PC0).y : (PC0).x);                     \
        bf16x8 a1_ = gen_chunk(half ? (PC1).y : (PC1).x);                     \
        __builtin_amdgcn_s_barrier();                                         \
        acc[0][0] = MFMA_(a0_, b0_, acc[0][0]);                               \
        acc[0][1] = MFMA_(a0_, b1_, acc[0][1]);                               \
        acc[1][0] = MFMA_(a1_, b0_, acc[1][0]);                               \
        acc[1][1] = MFMA_(a1_, b1_, acc[1][1]);                               \
        __builtin_amdgcn_s_barrier();                                         \
    }
#define PHASE1T(CUR, PC0, PC1)                                                \
    {                                                                         \
        const short* Bc_ = Bs + (CUR) * 8192;                                 \
        bf16x8 b0_ = *(const bf16x8*)(Bc_ + of1);                             \
        bf16x8 b1_ = *(const bf16x8*)(Bc_ + of1 + 4096);                      \
        bf16x8 a0_ = gen_chunk(half ? (PC0).w : (PC0).z);                     \
        bf16x8 a1_ = gen_chunk(half ? (PC1).w : (PC1).z);                     \
        __builtin_amdgcn_s_barrier();                                         \
        acc[0][0] = MFMA_(a0_, b0_, acc[0][0]);                               \
        acc[0][1] = MFMA_(a0_, b1_, acc[0][1]);                               \
        acc[1][0] = MFMA_(a1_, b0_, acc[1][0]);                               \
        acc[1][1] = MFMA_(a1_, b1_, acc[1][1]);                               \
    }

    float4 Pa0, Pa1, Pb0, Pb1;

    // ---- prologue: W(0)->buf0, x(0) regs; vmcnt(2) drains W(0); publish ----
    gload_lds16(pBa, Bs + bda);
    gload_lds16(pBb, Bs + bdb);
    Pa0 = *(const float4*)(xp0);
    Pa1 = *(const float4*)(xp0 + 16384);
    asm volatile("s_waitcnt vmcnt(2)" ::: "memory");
    __builtin_amdgcn_s_barrier();

    // ---- main: tiles 0..30 (static x-ring: even tiles Pa, odd Pb) ----
    for (int j = 0; j < 15; ++j) {
        PHASE0(0, 2 * j + 1, Pa0, Pa1);
        PHASE1(0, 2 * j + 1, Pa0, Pa1, Pb0, Pb1);
        PHASE0(1, 2 * j + 2, Pb0, Pb1);
        PHASE1(1, 2 * j + 2, Pb0, Pb1, Pa0, Pa1);
    }
    PHASE0(0, 31, Pa0, Pa1);
    PHASE1(0, 31, Pa0, Pa1, Pb0, Pb1);
    // ---- tail: tile 31 in buf1, consumes Pb ----
    PHASE0T(1, Pb0, Pb1);
    PHASE1T(1, Pb0, Pb1);
#undef PHASE0
#undef PHASE1
#undef PHASE0T
#undef PHASE1T
#undef MFMA_

    // ---- epilogue: 4-way split-K reduce per wm-group, [v][lane] slabs ----
    // slab s (0,1) at rbuf + s*4096: value v (0..63) of lane L at v*64 + L.
    float* rbuf = (float*)POOL;           // 8192 floats, exact fit
#pragma unroll
    for (int p = 0; p < 2; ++p) {
        __syncthreads();                  // pass 0: done with Bs; pass 1: prev done
        if (wm == p && kk >= 2) {         // kk2 -> slab0, kk3 -> slab1
            float* s_ = rbuf + (size_t)(kk - 2) * 4096 + lane;
#pragma unroll
            for (int fm = 0; fm < 2; ++fm)
#pragma unroll
                for (int fn = 0; fn < 2; ++fn)
#pragma unroll
                    for (int r = 0; r < 16; ++r)
                        s_[((fm * 2 + fn) * 16 + r) * 64] = acc[fm][fn][r];
        }
        __syncthreads();
        if (wm == p && kk < 2) {          // kk0 += slab0(kk2), kk1 += slab1(kk3)
            const float* s_ = rbuf + (size_t)kk * 4096 + lane;
#pragma unroll
            for (int fm = 0; fm < 2; ++fm)
#pragma unroll
                for (int fn = 0; fn < 2; ++fn)
#pragma unroll
                    for (int r = 0; r < 16; ++r)
                        acc[fm][fn][r] += s_[((fm * 2 + fn) * 16 + r) * 64];
        }
        __syncthreads();
        if (wm == p && kk == 1) {         // kk1 partial -> slab0
            float* s_ = rbuf + lane;
#pragma unroll
            for (int fm = 0; fm < 2; ++fm)
#pragma unroll
                for (int fn = 0; fn < 2; ++fn)
#pragma unroll
                    for (int r = 0; r < 16; ++r)
                        s_[((fm * 2 + fn) * 16 + r) * 64] = acc[fm][fn][r];
        }
        __syncthreads();
        if (wm == p && kk == 0) {
            const float* s_ = rbuf + lane;
            // C/D layout (32x32): col = lane&31, row = (r&3)+8*(r>>2)+4*(lane>>5)
#pragma unroll
            for (int fn = 0; fn < 2; ++fn) {
                int o = o0 + fn * 32 + l31;
                float bv = bias[o];
#pragma unroll
                for (int fm = 0; fm < 2; ++fm) {
#pragma unroll
                    for (int r = 0; r < 16; ++r) {
                        float v = acc[fm][fn][r] + s_[((fm * 2 + fn) * 16 + r) * 64] + bv;
                        int token = m0 + wm * 64 + fm * 32 + (r & 3) + 8 * (r >> 2) + 4 * half;
                        out[(size_t)token * OUT_FEAT + o] = v;
                    }
                }
            }
        }
    }
}

extern "C" void kernel_launch(void* const* d_in, const int* in_sizes, int n_in,
                              void* d_out, int out_size, void* d_ws, size_t ws_size,
                              hipStream_t stream) {
    const float* x            = (const float*)d_in[0];
    const float* coeff        = (const float*)d_in[1];
    const float* scale_base   = (const float*)d_in[2];
    const float* scale_spline = (const float*)d_in[3];
    const float* base_bias    = (const float*)d_in[4];
    float* out = (float*)d_out;

    short* Wb   = (short*)d_ws;                                  // 4 MB
    float* bias = (float*)((char*)d_ws + (size_t)OUT_FEAT * KDIM * 2);

    kan_prep<<<OUT_FEAT, 256, 0, stream>>>(coeff, scale_base, scale_spline, base_bias, Wb, bias);
    kan_gemm18<<<(NTOK / 128) * (OUT_FEAT / 64), 512, 0, stream>>>(x, Wb, bias, out);
}